// Round 3
// baseline (300.818 us; speedup 1.0000x reference)
//
#include <hip/hip_runtime.h>
#include <hip/hip_bf16.h>

#define SEQ  2048
#define DIM  2048
#define NQK  3072   // q(2048) + k(512) + v(512) columns
#define NH   32
#define NKV  8
#define HD   64

typedef __attribute__((ext_vector_type(8))) short s8v;
typedef __attribute__((ext_vector_type(4))) short s4v;
typedef __attribute__((ext_vector_type(4))) float f32x4;

__device__ __forceinline__ short f2bf_bits(float f) {
    __hip_bfloat16 b = __float2bfloat16(f);
    short s; __builtin_memcpy(&s, &b, 2); return s;
}
__device__ __forceinline__ float bfbits2f(short s) {
    __hip_bfloat16 b; __builtin_memcpy(&b, &s, 2);
    return __bfloat162float(b);
}
__device__ __forceinline__ f32x4 mfma16(s8v a, s8v b, f32x4 c) {
    return __builtin_amdgcn_mfma_f32_16x16x32_bf16(a, b, c, 0, 0, 0);
}
__device__ __forceinline__ void load16_to_lds(const void* g, void* l) {
    __builtin_amdgcn_global_load_lds(
        (const __attribute__((address_space(1))) void*)g,
        (__attribute__((address_space(3))) void*)l, 16, 0, 0);
}
__device__ __forceinline__ float fexp2(float x) {
    float y; asm("v_exp_f32 %0, %1" : "=v"(y) : "v"(x)); return y;
}

// ---------------- convert x (fp32 -> bf16) ----------------
__global__ void cvt_f32_bf16(const float* __restrict__ src, short* __restrict__ dst) {
    int i = (blockIdx.x * 256 + threadIdx.x) * 4;
    float4 v = *(const float4*)(src + i);
    s4v o;
    o.x = f2bf_bits(v.x); o.y = f2bf_bits(v.y);
    o.z = f2bf_bits(v.z); o.w = f2bf_bits(v.w);
    *(s4v*)(dst + i) = o;
}

// ---------------- transpose + convert (K x Cs fp32 -> Cs x 2048 bf16) ----------------
__global__ void transpose_cvt(const float* __restrict__ src, short* __restrict__ dst, int Cs) {
    __shared__ float tile[32][33];
    int bx = blockIdx.x * 32, by = blockIdx.y * 32;
    int tx = threadIdx.x, ty = threadIdx.y;   // 32 x 8
    #pragma unroll
    for (int j = 0; j < 32; j += 8)
        tile[ty + j][tx] = src[(size_t)(by + ty + j) * Cs + bx + tx];
    __syncthreads();
    #pragma unroll
    for (int j = 0; j < 32; j += 8)
        dst[(size_t)(bx + ty + j) * 2048 + by + tx] = f2bf_bits(tile[tx][ty + j]);
}

// ---------------- GEMM: A (MxK bf16) @ BT (NxK bf16)^T, BM=128 BN=64 BK=64 ----------------
// MODE 0: QKV — bf16 out with fused RoPE (cols<2560) and transposed V write (cols>=2560)
// MODE 1: fp32 out plain (out-projection)
template<int MODE>
__global__ __launch_bounds__(256, 3)
void gemm_bt(const short* __restrict__ A, const short* __restrict__ BT,
             void* __restrict__ C, int M, int N, int K, int nx,
             short* __restrict__ vT,
             const float* __restrict__ fc, const float* __restrict__ fs)
{
    __shared__ short As[128 * 64];
    __shared__ short Bs[64 * 64];
    // bijective XCD swizzle (grid % 8 == 0): same-XCD blocks share the A panel
    const int nwg = gridDim.x;
    const int orig = blockIdx.x;
    const int wg = (orig & 7) * (nwg >> 3) + (orig >> 3);
    const int bx = wg % nx, by = wg / nx;
    const int bm = by * 128, bn = bx * 64;

    const int lane = threadIdx.x & 63;
    const int wid  = threadIdx.x >> 6;
    const int r = lane & 15, g = lane >> 4;
    const int wm = (wid >> 1) * 64, wn = (wid & 1) * 32;

    f32x4 acc[4][2];
    #pragma unroll
    for (int i = 0; i < 4; ++i)
        #pragma unroll
        for (int j = 0; j < 2; ++j) acc[i][j] = (f32x4){0.f, 0.f, 0.f, 0.f};

    const int srl = lane >> 3;            // 0..7
    const int scol = (lane & 7) * 8;

    for (int k0 = 0; k0 < K; k0 += 64) {
        #pragma unroll
        for (int s2 = 0; s2 < 4; ++s2) {  // A: wave stages rows wid*32 .. +32
            int row = wid * 32 + s2 * 8 + srl;
            load16_to_lds(A + (size_t)(bm + row) * K + k0 + scol, As + (wid * 4 + s2) * 512);
        }
        #pragma unroll
        for (int s2 = 0; s2 < 2; ++s2) {  // B: wave stages rows wid*16 .. +16
            int row = wid * 16 + s2 * 8 + srl;
            load16_to_lds(BT + (size_t)(bn + row) * K + k0 + scol, Bs + (wid * 2 + s2) * 512);
        }
        __syncthreads();
        #pragma unroll
        for (int kk = 0; kk < 64; kk += 32) {
            s8v a[4], b[2];
            #pragma unroll
            for (int t = 0; t < 4; ++t)
                a[t] = *(const s8v*)&As[(wm + t * 16 + r) * 64 + kk + g * 8];
            #pragma unroll
            for (int t = 0; t < 2; ++t)
                b[t] = *(const s8v*)&Bs[(wn + t * 16 + r) * 64 + kk + g * 8];
            __builtin_amdgcn_s_setprio(1);
            #pragma unroll
            for (int i = 0; i < 4; ++i)
                #pragma unroll
                for (int j = 0; j < 2; ++j)
                    acc[i][j] = mfma16(a[i], b[j], acc[i][j]);
            __builtin_amdgcn_s_setprio(0);
        }
        __syncthreads();
    }

    if (MODE == 1) {
        #pragma unroll
        for (int i = 0; i < 4; ++i)
            #pragma unroll
            for (int j = 0; j < 2; ++j)
                #pragma unroll
                for (int q = 0; q < 4; ++q) {
                    int row = bm + wm + i * 16 + g * 4 + q;
                    int col = bn + wn + j * 16 + r;
                    ((float*)C)[(size_t)row * N + col] = acc[i][j][q];
                }
    } else {
        short* qkvO = (short*)C;
        if (bn >= 2560) {
            // V region: write transposed vT[col-2560][row], 4 rows contiguous
            #pragma unroll
            for (int i = 0; i < 4; ++i)
                #pragma unroll
                for (int j = 0; j < 2; ++j) {
                    int row = bm + wm + i * 16 + g * 4;
                    int col = bn + wn + j * 16 + r - 2560;
                    s4v o;
                    #pragma unroll
                    for (int q = 0; q < 4; ++q) o[q] = f2bf_bits(acc[i][j][q]);
                    *(s4v*)&vT[(size_t)col * 2048 + row] = o;
                }
        } else {
            // Q/K region: fused RoPE. col pairs live in adjacent lanes (r, r^1).
            #pragma unroll
            for (int i = 0; i < 4; ++i)
                #pragma unroll
                for (int j = 0; j < 2; ++j) {
                    int row = bm + wm + i * 16 + g * 4;
                    int col = bn + wn + j * 16 + r;
                    int ii  = (col & 63) >> 1;
                    bool odd = (col & 1);
                    #pragma unroll
                    for (int q = 0; q < 4; ++q) {
                        float v = acc[i][j][q];
                        float p = __shfl_xor(v, 1, 64);
                        float c  = fc[(size_t)(row + q) * 32 + ii];
                        float sn = fs[(size_t)(row + q) * 32 + ii];
                        float outv = odd ? (p * sn + v * c) : (v * c - p * sn);
                        qkvO[(size_t)(row + q) * NQK + col] = f2bf_bits(outv);
                    }
                }
        }
    }
}

// ---------------- flash attention: 1 head x 128 q-rows per block ----------------
// exp2-domain online softmax, defer-max (THR=8 in log2 domain)
#define SCL 0.18033688f   // 0.125 * log2(e)
__global__ __launch_bounds__(256, 4)
void flash_attn(const short* __restrict__ qkv, const short* __restrict__ vT,
                short* __restrict__ O) {
    const int h  = blockIdx.x;                            // 0..31
    const int qi = (int)gridDim.y - 1 - (int)blockIdx.y;  // longest blocks first
    const int qb = qi * 128;
    const int kh = h >> 2;                                // GQA kv head
    const int lane = threadIdx.x & 63;
    const int wid  = threadIdx.x >> 6;
    const int r = lane & 15, g = lane >> 4;

    __shared__ short Ks[64][72];        // [kpos][d]
    __shared__ short Vt[64][72];        // [d][kpos]
    __shared__ short Pl[4][32][72];     // per-wave P [qrow(32)][kpos]

    // Q fragments: wave owns rows qb + wid*32 .. +32 (two 16-row groups)
    s8v qf[2][2];
    #pragma unroll
    for (int i = 0; i < 2; ++i) {
        const short* qrow = qkv + (size_t)(qb + wid * 32 + i * 16 + r) * NQK + h * 64;
        qf[i][0] = *(const s8v*)(qrow + g * 8);
        qf[i][1] = *(const s8v*)(qrow + 32 + g * 8);
    }

    float m[2][4], l[2][4];
    f32x4 o[2][4];
    #pragma unroll
    for (int i = 0; i < 2; ++i)
        #pragma unroll
        for (int q = 0; q < 4; ++q) { m[i][q] = -1e30f; l[i][q] = 0.f; }
    #pragma unroll
    for (int i = 0; i < 2; ++i)
        #pragma unroll
        for (int t = 0; t < 4; ++t) o[i][t] = (f32x4){0.f, 0.f, 0.f, 0.f};

    const int tr = threadIdx.x >> 2;          // 0..63
    const int tc = (threadIdx.x & 3) * 16;    // 0,16,32,48

    const int nkt = 2 * qi + 2;
    for (int kt = 0; kt < nkt; ++kt) {
        { // stage K tile [kpos][d] and V^T tile [d][kpos]
            const short* kg = qkv + (size_t)(kt * 64 + tr) * NQK + 2048 + kh * 64 + tc;
            *(s8v*)&Ks[tr][tc]     = *(const s8v*)kg;
            *(s8v*)&Ks[tr][tc + 8] = *(const s8v*)(kg + 8);
            const short* vg = vT + (size_t)(kh * 64 + tr) * 2048 + kt * 64 + tc;
            *(s8v*)&Vt[tr][tc]     = *(const s8v*)vg;
            *(s8v*)&Vt[tr][tc + 8] = *(const s8v*)(vg + 8);
        }
        __syncthreads();

        const bool diag = (kt >= nkt - 2);
        #pragma unroll
        for (int i = 0; i < 2; ++i) {
            // S = Q @ K^T  (16 x 64)
            f32x4 s[4];
            __builtin_amdgcn_s_setprio(1);
            #pragma unroll
            for (int t = 0; t < 4; ++t) {
                s8v kb0 = *(const s8v*)&Ks[t * 16 + r][g * 8];
                s8v kb1 = *(const s8v*)&Ks[t * 16 + r][32 + g * 8];
                f32x4 z = (f32x4){0.f, 0.f, 0.f, 0.f};
                z = mfma16(qf[i][0], kb0, z);
                z = mfma16(qf[i][1], kb1, z);
                s[t] = z;
            }
            __builtin_amdgcn_s_setprio(0);

            // scale into log2 domain + causal mask
            #pragma unroll
            for (int t = 0; t < 4; ++t)
                #pragma unroll
                for (int q = 0; q < 4; ++q) {
                    float v = s[t][q] * SCL;
                    if (diag) {
                        int qrow = qb + wid * 32 + i * 16 + g * 4 + q;
                        int kpos = kt * 64 + t * 16 + r;
                        if (kpos > qrow) v = -1e30f;
                    }
                    s[t][q] = v;
                }

            // row max
            float pm[4];
            #pragma unroll
            for (int q = 0; q < 4; ++q) {
                float v = fmaxf(fmaxf(s[0][q], s[1][q]), fmaxf(s[2][q], s[3][q]));
                #pragma unroll
                for (int off = 1; off < 16; off <<= 1) v = fmaxf(v, __shfl_xor(v, off, 64));
                pm[q] = v;
            }
            // defer-max: rescale only when max grew past threshold
            bool need = (pm[0] > m[i][0] + 8.f) || (pm[1] > m[i][1] + 8.f) ||
                        (pm[2] > m[i][2] + 8.f) || (pm[3] > m[i][3] + 8.f);
            if (__any(need)) {
                #pragma unroll
                for (int q = 0; q < 4; ++q) {
                    float mn = fmaxf(m[i][q], pm[q]);
                    float al = fexp2(m[i][q] - mn);
                    m[i][q] = mn;
                    l[i][q] *= al;
                    #pragma unroll
                    for (int t = 0; t < 4; ++t) o[i][t][q] *= al;
                }
            }
            // p = exp2(s - m), row sums, stash P to LDS
            #pragma unroll
            for (int t = 0; t < 4; ++t)
                #pragma unroll
                for (int q = 0; q < 4; ++q)
                    s[t][q] = fexp2(s[t][q] - m[i][q]);
            #pragma unroll
            for (int q = 0; q < 4; ++q) {
                float v = (s[0][q] + s[1][q]) + (s[2][q] + s[3][q]);
                #pragma unroll
                for (int off = 1; off < 16; off <<= 1) v += __shfl_xor(v, off, 64);
                l[i][q] += v;
            }
            #pragma unroll
            for (int t = 0; t < 4; ++t)
                #pragma unroll
                for (int q = 0; q < 4; ++q)
                    Pl[wid][i * 16 + g * 4 + q][t * 16 + r] = f2bf_bits(s[t][q]);
        }
        asm volatile("s_waitcnt lgkmcnt(0)" ::: "memory");

        // O += P @ V  (both groups)
        __builtin_amdgcn_s_setprio(1);
        #pragma unroll
        for (int i = 0; i < 2; ++i) {
            s8v pa0 = *(const s8v*)&Pl[wid][i * 16 + r][g * 8];
            s8v pa1 = *(const s8v*)&Pl[wid][i * 16 + r][32 + g * 8];
            #pragma unroll
            for (int t = 0; t < 4; ++t) {
                s8v vb0 = *(const s8v*)&Vt[t * 16 + r][g * 8];
                s8v vb1 = *(const s8v*)&Vt[t * 16 + r][32 + g * 8];
                o[i][t] = mfma16(pa0, vb0, o[i][t]);
                o[i][t] = mfma16(pa1, vb1, o[i][t]);
            }
        }
        __builtin_amdgcn_s_setprio(0);
        __syncthreads();
    }

    // epilogue: O * (1/l) -> bf16 at [s][h*64+d]
    #pragma unroll
    for (int i = 0; i < 2; ++i) {
        float rl[4];
        #pragma unroll
        for (int q = 0; q < 4; ++q) rl[q] = __builtin_amdgcn_rcpf(l[i][q]);
        #pragma unroll
        for (int t = 0; t < 4; ++t)
            #pragma unroll
            for (int q = 0; q < 4; ++q) {
                float val = o[i][t][q] * rl[q];
                O[(size_t)(qb + wid * 32 + i * 16 + g * 4 + q) * 2048 + h * 64 + t * 16 + r] = f2bf_bits(val);
            }
    }
}

extern "C" void kernel_launch(void* const* d_in, const int* in_sizes, int n_in,
                              void* d_out, int out_size, void* d_ws, size_t ws_size,
                              hipStream_t stream)
{
    const float* x  = (const float*)d_in[0];
    const float* fc = (const float*)d_in[1];
    const float* fs = (const float*)d_in[2];
    // d_in[3] = mask (unused; causal applied analytically)
    const float* wq = (const float*)d_in[4];
    const float* wk = (const float*)d_in[5];
    const float* wv = (const float*)d_in[6];
    const float* wo = (const float*)d_in[7];
    float* out = (float*)d_out;

    char* ws = (char*)d_ws;
    short* xb    = (short*)(ws);                         //  8 MB: 2048x2048
    short* wqkvT = (short*)(ws + 8  * 1024 * 1024);      // 12 MB: 3072x2048
    short* woT   = (short*)(ws + 20 * 1024 * 1024);      //  8 MB: 2048x2048
    short* qkv   = (short*)(ws + 28 * 1024 * 1024);      // 12 MB: 2048x3072 (v region unused)
    short* vT    = (short*)(ws + 40 * 1024 * 1024);      //  2 MB: 512x2048 (V transposed)
    short* attnO = (short*)(ws + 42 * 1024 * 1024);      //  8 MB: 2048x2048

    dim3 tb(32, 8);
    cvt_f32_bf16<<<4096, 256, 0, stream>>>(x, xb);
    transpose_cvt<<<dim3(64, 64), tb, 0, stream>>>(wq, wqkvT, 2048);
    transpose_cvt<<<dim3(16, 64), tb, 0, stream>>>(wk, wqkvT + 2048 * 2048, 512);
    transpose_cvt<<<dim3(16, 64), tb, 0, stream>>>(wv, wqkvT + 2560 * 2048, 512);
    transpose_cvt<<<dim3(64, 64), tb, 0, stream>>>(wo, woT, 2048);

    // QKV: grid 48*16=768 blocks ; out-proj: 32*16=512 blocks (both %8==0)
    gemm_bt<0><<<768, 256, 0, stream>>>(xb, wqkvT, qkv, 2048, 3072, 2048, 48, vT, fc, fs);
    flash_attn<<<dim3(32, 16), 256, 0, stream>>>(qkv, vT, attnO);
    gemm_bt<1><<<512, 256, 0, stream>>>(attnO, woT, out, 2048, 2048, 2048, 32, nullptr, nullptr, nullptr);
}

// Round 4
// 272.307 us; speedup vs baseline: 1.1047x; 1.1047x over previous
//
#include <hip/hip_runtime.h>
#include <hip/hip_bf16.h>

#define SEQ  2048
#define DIM  2048
#define NQK  3072   // q(2048) + k(512) + v(512) columns
#define NH   32
#define NKV  8
#define HD   64

typedef __attribute__((ext_vector_type(8))) short s8v;
typedef __attribute__((ext_vector_type(4))) short s4v;
typedef __attribute__((ext_vector_type(4))) float f32x4;

__device__ __forceinline__ short f2bf_bits(float f) {
    __hip_bfloat16 b = __float2bfloat16(f);
    short s; __builtin_memcpy(&s, &b, 2); return s;
}
__device__ __forceinline__ float bfbits2f(short s) {
    __hip_bfloat16 b; __builtin_memcpy(&b, &s, 2);
    return __bfloat162float(b);
}
__device__ __forceinline__ f32x4 mfma16(s8v a, s8v b, f32x4 c) {
    return __builtin_amdgcn_mfma_f32_16x16x32_bf16(a, b, c, 0, 0, 0);
}
__device__ __forceinline__ void load16_to_lds(const void* g, void* l) {
    __builtin_amdgcn_global_load_lds(
        (const __attribute__((address_space(1))) void*)g,
        (__attribute__((address_space(3))) void*)l, 16, 0, 0);
}
__device__ __forceinline__ float fexp2(float x) {
    float y; asm("v_exp_f32 %0, %1" : "=v"(y) : "v"(x)); return y;
}

// ---------------- convert x (fp32 -> bf16) ----------------
__global__ void cvt_f32_bf16(const float* __restrict__ src, short* __restrict__ dst) {
    int i = (blockIdx.x * 256 + threadIdx.x) * 4;
    float4 v = *(const float4*)(src + i);
    s4v o;
    o.x = f2bf_bits(v.x); o.y = f2bf_bits(v.y);
    o.z = f2bf_bits(v.z); o.w = f2bf_bits(v.w);
    *(s4v*)(dst + i) = o;
}

// ---------------- transpose + convert (K x Cs fp32 -> Cs x 2048 bf16) ----------------
__global__ void transpose_cvt(const float* __restrict__ src, short* __restrict__ dst, int Cs) {
    __shared__ float tile[32][33];
    int bx = blockIdx.x * 32, by = blockIdx.y * 32;
    int tx = threadIdx.x, ty = threadIdx.y;   // 32 x 8
    #pragma unroll
    for (int j = 0; j < 32; j += 8)
        tile[ty + j][tx] = src[(size_t)(by + ty + j) * Cs + bx + tx];
    __syncthreads();
    #pragma unroll
    for (int j = 0; j < 32; j += 8)
        dst[(size_t)(bx + ty + j) * 2048 + by + tx] = f2bf_bits(tile[tx][ty + j]);
}

// ---------------- GEMM: A (MxK bf16) @ BT (NxK bf16)^T, 128x128 tile, split-K=2 ----------------
// Each block computes half of K; bf16 partials go to P0 or P1.
__global__ __launch_bounds__(256, 3)
void gemm_bt(const short* __restrict__ A, const short* __restrict__ BT,
             short* __restrict__ P0, short* __restrict__ P1,
             int N, int K, int nx)
{
    __shared__ short As[128 * 64];
    __shared__ short Bs[128 * 64];
    // bijective XCD swizzle (grid % 8 == 0)
    const int nwg = gridDim.x;
    const int orig = blockIdx.x;
    const int wg = (orig & 7) * (nwg >> 3) + (orig >> 3);
    const int ks  = wg & 1;            // split-K slice
    const int bxy = wg >> 1;
    const int bm = (bxy / nx) * 128, bn = (bxy % nx) * 128;

    const int lane = threadIdx.x & 63;
    const int wid  = threadIdx.x >> 6;
    const int r = lane & 15, g = lane >> 4;
    const int wm = (wid >> 1) * 64, wn = (wid & 1) * 64;

    f32x4 acc[4][4];
    #pragma unroll
    for (int i = 0; i < 4; ++i)
        #pragma unroll
        for (int j = 0; j < 4; ++j) acc[i][j] = (f32x4){0.f, 0.f, 0.f, 0.f};

    const int srow = wid * 32 + (lane >> 3);
    const int scol = (lane & 7) * 8;
    const int kbeg = ks * (K >> 1), kend = kbeg + (K >> 1);

    for (int k0 = kbeg; k0 < kend; k0 += 64) {
        #pragma unroll
        for (int s2 = 0; s2 < 4; ++s2) {
            int row = srow + s2 * 8;
            int seg = wid * 4 + s2;
            load16_to_lds(A  + (size_t)(bm + row) * K + k0 + scol, As + seg * 512);
            load16_to_lds(BT + (size_t)(bn + row) * K + k0 + scol, Bs + seg * 512);
        }
        __syncthreads();
        #pragma unroll
        for (int kk = 0; kk < 64; kk += 32) {
            s8v a[4], b[4];
            #pragma unroll
            for (int t = 0; t < 4; ++t)
                a[t] = *(const s8v*)&As[(wm + t * 16 + r) * 64 + kk + g * 8];
            #pragma unroll
            for (int t = 0; t < 4; ++t)
                b[t] = *(const s8v*)&Bs[(wn + t * 16 + r) * 64 + kk + g * 8];
            __builtin_amdgcn_s_setprio(1);
            #pragma unroll
            for (int i = 0; i < 4; ++i)
                #pragma unroll
                for (int j = 0; j < 4; ++j)
                    acc[i][j] = mfma16(a[i], b[j], acc[i][j]);
            __builtin_amdgcn_s_setprio(0);
        }
        __syncthreads();
    }

    short* P = ks ? P1 : P0;
    #pragma unroll
    for (int i = 0; i < 4; ++i)
        #pragma unroll
        for (int j = 0; j < 4; ++j)
            #pragma unroll
            for (int q = 0; q < 4; ++q) {
                int row = bm + wm + i * 16 + g * 4 + q;
                int col = bn + wn + j * 16 + r;
                P[(size_t)row * N + col] = f2bf_bits(acc[i][j][q]);
            }
}

// ---------------- epilogue: add split-K partials + RoPE -> qkv (Q,K cols 0..2559) ----------------
__global__ void rope_add(const short* __restrict__ P0, const short* __restrict__ P1,
                         short* __restrict__ qkv,
                         const float* __restrict__ fc, const float* __restrict__ fs) {
    int idx = blockIdx.x * 256 + threadIdx.x;   // 2048 rows x 320 col-groups
    int row = idx / 320;
    int col = (idx - row * 320) * 8;
    s8v a = *(const s8v*)(P0 + (size_t)row * NQK + col);
    s8v b = *(const s8v*)(P1 + (size_t)row * NQK + col);
    int p0 = (col & 63) >> 1;
    s8v o;
    #pragma unroll
    for (int k = 0; k < 4; ++k) {
        float xe = bfbits2f(a[2 * k])     + bfbits2f(b[2 * k]);
        float xo = bfbits2f(a[2 * k + 1]) + bfbits2f(b[2 * k + 1]);
        float c  = fc[row * 32 + p0 + k];
        float sn = fs[row * 32 + p0 + k];
        o[2 * k]     = f2bf_bits(xe * c - xo * sn);
        o[2 * k + 1] = f2bf_bits(xe * sn + xo * c);
    }
    *(s8v*)(qkv + (size_t)row * NQK + col) = o;
}

// ---------------- epilogue: add partials + transpose V -> vT[512][2048] ----------------
__global__ void vT_add(const short* __restrict__ P0, const short* __restrict__ P1,
                       short* __restrict__ vT) {
    __shared__ float tile[32][33];
    int bx = blockIdx.x * 32;   // V col block (0..511)
    int by = blockIdx.y * 32;   // row block (0..2047)
    int tx = threadIdx.x, ty = threadIdx.y;   // 32 x 8
    #pragma unroll
    for (int j = 0; j < 32; j += 8) {
        size_t off = (size_t)(by + ty + j) * NQK + 2560 + bx + tx;
        tile[ty + j][tx] = bfbits2f(P0[off]) + bfbits2f(P1[off]);
    }
    __syncthreads();
    #pragma unroll
    for (int j = 0; j < 32; j += 8)
        vT[(size_t)(bx + ty + j) * 2048 + by + tx] = f2bf_bits(tile[tx][ty + j]);
}

// ---------------- epilogue: add partials -> fp32 out ----------------
__global__ void add_out(const short* __restrict__ R0, const short* __restrict__ R1,
                        float* __restrict__ out) {
    int i = (blockIdx.x * 256 + threadIdx.x) * 8;
    s8v a = *(const s8v*)(R0 + i);
    s8v b = *(const s8v*)(R1 + i);
    float4 o0, o1;
    o0.x = bfbits2f(a[0]) + bfbits2f(b[0]);
    o0.y = bfbits2f(a[1]) + bfbits2f(b[1]);
    o0.z = bfbits2f(a[2]) + bfbits2f(b[2]);
    o0.w = bfbits2f(a[3]) + bfbits2f(b[3]);
    o1.x = bfbits2f(a[4]) + bfbits2f(b[4]);
    o1.y = bfbits2f(a[5]) + bfbits2f(b[5]);
    o1.z = bfbits2f(a[6]) + bfbits2f(b[6]);
    o1.w = bfbits2f(a[7]) + bfbits2f(b[7]);
    *(float4*)(out + i)     = o0;
    *(float4*)(out + i + 4) = o1;
}

// ---------------- flash attention: 1 head x 64 q-rows per block ----------------
// exp2-domain online softmax + defer-max (THR=8 in log2 domain)
#define SCL 0.18033688f   // 0.125 * log2(e)
__global__ __launch_bounds__(256, 4)
void flash_attn(const short* __restrict__ qkv, const short* __restrict__ vT,
                short* __restrict__ O) {
    const int h  = blockIdx.x;                            // 0..31
    const int qi = (int)gridDim.y - 1 - (int)blockIdx.y;  // longest blocks first
    const int qb = qi * 64;
    const int kh = h >> 2;                                // GQA kv head
    const int lane = threadIdx.x & 63;
    const int wid  = threadIdx.x >> 6;
    const int r = lane & 15, g = lane >> 4;

    __shared__ short Ks[64][72];        // [kpos][d]
    __shared__ short Vt[64][72];        // [d][kpos]
    __shared__ short Pl[4][16][72];     // per-wave P [qrow][kpos]

    s8v qf0, qf1;
    {
        const short* qrow = qkv + (size_t)(qb + wid * 16 + r) * NQK + h * 64;
        qf0 = *(const s8v*)(qrow + g * 8);
        qf1 = *(const s8v*)(qrow + 32 + g * 8);
    }

    float m[4], l[4];
    f32x4 o[4];
    #pragma unroll
    for (int q = 0; q < 4; ++q) { m[q] = -1e30f; l[q] = 0.f; }
    #pragma unroll
    for (int t = 0; t < 4; ++t) o[t] = (f32x4){0.f, 0.f, 0.f, 0.f};

    const int tr = threadIdx.x >> 2;
    const int tc = (threadIdx.x & 3) * 16;

    const int nkt = qi + 1;
    for (int kt = 0; kt < nkt; ++kt) {
        {
            const short* kg = qkv + (size_t)(kt * 64 + tr) * NQK + 2048 + kh * 64 + tc;
            *(s8v*)&Ks[tr][tc]     = *(const s8v*)kg;
            *(s8v*)&Ks[tr][tc + 8] = *(const s8v*)(kg + 8);
            const short* vg = vT + (size_t)(kh * 64 + tr) * 2048 + kt * 64 + tc;
            *(s8v*)&Vt[tr][tc]     = *(const s8v*)vg;
            *(s8v*)&Vt[tr][tc + 8] = *(const s8v*)(vg + 8);
        }
        __syncthreads();

        // S = Q @ K^T  (16 x 64 per wave)
        f32x4 s[4];
        __builtin_amdgcn_s_setprio(1);
        #pragma unroll
        for (int t = 0; t < 4; ++t) {
            s8v kb0 = *(const s8v*)&Ks[t * 16 + r][g * 8];
            s8v kb1 = *(const s8v*)&Ks[t * 16 + r][32 + g * 8];
            f32x4 z = (f32x4){0.f, 0.f, 0.f, 0.f};
            z = mfma16(qf0, kb0, z);
            z = mfma16(qf1, kb1, z);
            s[t] = z;
        }
        __builtin_amdgcn_s_setprio(0);

        // scale into log2 domain + causal mask (diagonal tile only)
        const bool diag = (kt == nkt - 1);
        #pragma unroll
        for (int t = 0; t < 4; ++t)
            #pragma unroll
            for (int q = 0; q < 4; ++q) {
                float v = s[t][q] * SCL;
                if (diag) {
                    int qrow = qb + wid * 16 + g * 4 + q;
                    int kpos = kt * 64 + t * 16 + r;
                    if (kpos > qrow) v = -1e30f;
                }
                s[t][q] = v;
            }

        // row max
        float pm[4];
        #pragma unroll
        for (int q = 0; q < 4; ++q) {
            float v = fmaxf(fmaxf(s[0][q], s[1][q]), fmaxf(s[2][q], s[3][q]));
            #pragma unroll
            for (int off = 1; off < 16; off <<= 1) v = fmaxf(v, __shfl_xor(v, off, 64));
            pm[q] = v;
        }
        // defer-max: rescale only when max grew past threshold
        bool need = (pm[0] > m[0] + 8.f) || (pm[1] > m[1] + 8.f) ||
                    (pm[2] > m[2] + 8.f) || (pm[3] > m[3] + 8.f);
        if (__any(need)) {
            #pragma unroll
            for (int q = 0; q < 4; ++q) {
                float mn = fmaxf(m[q], pm[q]);
                float al = fexp2(m[q] - mn);
                m[q] = mn;
                l[q] *= al;
                #pragma unroll
                for (int t = 0; t < 4; ++t) o[t][q] *= al;
            }
        }
        // p = exp2(s - m), row sums, stash P
        #pragma unroll
        for (int t = 0; t < 4; ++t)
            #pragma unroll
            for (int q = 0; q < 4; ++q)
                s[t][q] = fexp2(s[t][q] - m[q]);
        #pragma unroll
        for (int q = 0; q < 4; ++q) {
            float v = (s[0][q] + s[1][q]) + (s[2][q] + s[3][q]);
            #pragma unroll
            for (int off = 1; off < 16; off <<= 1) v += __shfl_xor(v, off, 64);
            l[q] += v;
        }
        #pragma unroll
        for (int t = 0; t < 4; ++t)
            #pragma unroll
            for (int q = 0; q < 4; ++q)
                Pl[wid][g * 4 + q][t * 16 + r] = f2bf_bits(s[t][q]);
        asm volatile("s_waitcnt lgkmcnt(0)" ::: "memory");

        // O += P @ V
        s8v pa0 = *(const s8v*)&Pl[wid][r][g * 8];
        s8v pa1 = *(const s8v*)&Pl[wid][r][32 + g * 8];
        __builtin_amdgcn_s_setprio(1);
        #pragma unroll
        for (int t = 0; t < 4; ++t) {
            s8v vb0 = *(const s8v*)&Vt[t * 16 + r][g * 8];
            s8v vb1 = *(const s8v*)&Vt[t * 16 + r][32 + g * 8];
            o[t] = mfma16(pa0, vb0, o[t]);
            o[t] = mfma16(pa1, vb1, o[t]);
        }
        __builtin_amdgcn_s_setprio(0);
        __syncthreads();
    }

    // epilogue
    float rl[4];
    #pragma unroll
    for (int q = 0; q < 4; ++q) rl[q] = __builtin_amdgcn_rcpf(l[q]);
    #pragma unroll
    for (int t = 0; t < 4; ++t)
        #pragma unroll
        for (int q = 0; q < 4; ++q) {
            float val = o[t][q] * rl[q];
            O[(size_t)(qb + wid * 16 + g * 4 + q) * 2048 + h * 64 + t * 16 + r] = f2bf_bits(val);
        }
}

extern "C" void kernel_launch(void* const* d_in, const int* in_sizes, int n_in,
                              void* d_out, int out_size, void* d_ws, size_t ws_size,
                              hipStream_t stream)
{
    const float* x  = (const float*)d_in[0];
    const float* fc = (const float*)d_in[1];
    const float* fs = (const float*)d_in[2];
    // d_in[3] = mask (unused; causal applied analytically)
    const float* wq = (const float*)d_in[4];
    const float* wk = (const float*)d_in[5];
    const float* wv = (const float*)d_in[6];
    const float* wo = (const float*)d_in[7];
    float* out = (float*)d_out;

    char* ws = (char*)d_ws;
    short* xb    = (short*)(ws);                         //  8 MB: 2048x2048
    short* wqkvT = (short*)(ws + 8  * 1024 * 1024);      // 12 MB: 3072x2048
    short* woT   = (short*)(ws + 20 * 1024 * 1024);      //  8 MB: 2048x2048
    short* qkv   = (short*)(ws + 28 * 1024 * 1024);      // 12 MB: 2048x3072 (V cols unused)
    short* vT    = (short*)(ws + 40 * 1024 * 1024);      //  2 MB: 512x2048
    short* attnO = (short*)(ws + 42 * 1024 * 1024);      //  8 MB: 2048x2048
    short* P0    = (short*)(ws + 50 * 1024 * 1024);      // 13 MB: 2048x3072 partial
    short* P1    = (short*)(ws + 63 * 1024 * 1024);      // 13 MB: 2048x3072 partial

    dim3 tb(32, 8);
    cvt_f32_bf16<<<4096, 256, 0, stream>>>(x, xb);
    transpose_cvt<<<dim3(64, 64), tb, 0, stream>>>(wq, wqkvT, 2048);
    transpose_cvt<<<dim3(16, 64), tb, 0, stream>>>(wk, wqkvT + 2048 * 2048, 512);
    transpose_cvt<<<dim3(16, 64), tb, 0, stream>>>(wv, wqkvT + 2560 * 2048, 512);
    transpose_cvt<<<dim3(64, 64), tb, 0, stream>>>(wo, woT, 2048);

    // QKV projection, split-K=2: grid 24x16x2 = 768 blocks
    gemm_bt<<<768, 256, 0, stream>>>(xb, wqkvT, P0, P1, 3072, 2048, 24);
    rope_add<<<2560, 256, 0, stream>>>(P0, P1, qkv, fc, fs);
    vT_add<<<dim3(16, 64), tb, 0, stream>>>(P0, P1, vT);

    flash_attn<<<dim3(32, 32), 256, 0, stream>>>(qkv, vT, attnO);

    // out projection, split-K=2: grid 16x16x2 = 512 blocks (reuse P0/P1)
    gemm_bt<<<512, 256, 0, stream>>>(attnO, woT, P0, P1, 2048, 2048, 16);
    add_out<<<2048, 256, 0, stream>>>(P0, P1, out);
}

// Round 5
// 252.661 us; speedup vs baseline: 1.1906x; 1.0778x over previous
//
#include <hip/hip_runtime.h>
#include <hip/hip_bf16.h>

#define SEQ  2048
#define DIM  2048
#define NQK  3072   // q(2048) + k(512) + v(512) columns
#define NH   32
#define NKV  8
#define HD   64
#define SCL  0.18033688f   // 0.125 * log2(e), folded into Q at rope_add

typedef __attribute__((ext_vector_type(8))) short s8v;
typedef __attribute__((ext_vector_type(4))) short s4v;
typedef __attribute__((ext_vector_type(4))) float f32x4;

__device__ __forceinline__ short f2bf_bits(float f) {
    __hip_bfloat16 b = __float2bfloat16(f);
    short s; __builtin_memcpy(&s, &b, 2); return s;
}
__device__ __forceinline__ float bfbits2f(short s) {
    __hip_bfloat16 b; __builtin_memcpy(&b, &s, 2);
    return __bfloat162float(b);
}
__device__ __forceinline__ f32x4 mfma16(s8v a, s8v b, f32x4 c) {
    return __builtin_amdgcn_mfma_f32_16x16x32_bf16(a, b, c, 0, 0, 0);
}
__device__ __forceinline__ void load16_to_lds(const void* g, void* l) {
    __builtin_amdgcn_global_load_lds(
        (const __attribute__((address_space(1))) void*)g,
        (__attribute__((address_space(3))) void*)l, 16, 0, 0);
}
__device__ __forceinline__ float fexp2(float x) {
    float y; asm("v_exp_f32 %0, %1" : "=v"(y) : "v"(x)); return y;
}

// ---------------- convert x (fp32 -> bf16) ----------------
__global__ void cvt_f32_bf16(const float* __restrict__ src, short* __restrict__ dst) {
    int i = (blockIdx.x * 256 + threadIdx.x) * 4;
    float4 v = *(const float4*)(src + i);
    s4v o;
    o.x = f2bf_bits(v.x); o.y = f2bf_bits(v.y);
    o.z = f2bf_bits(v.z); o.w = f2bf_bits(v.w);
    *(s4v*)(dst + i) = o;
}

// ---------------- transpose + convert (K x Cs fp32 -> Cs x 2048 bf16) ----------------
__global__ void transpose_cvt(const float* __restrict__ src, short* __restrict__ dst, int Cs) {
    __shared__ float tile[32][33];
    int bx = blockIdx.x * 32, by = blockIdx.y * 32;
    int tx = threadIdx.x, ty = threadIdx.y;   // 32 x 8
    #pragma unroll
    for (int j = 0; j < 32; j += 8)
        tile[ty + j][tx] = src[(size_t)(by + ty + j) * Cs + bx + tx];
    __syncthreads();
    #pragma unroll
    for (int j = 0; j < 32; j += 8)
        dst[(size_t)(bx + ty + j) * 2048 + by + tx] = f2bf_bits(tile[tx][ty + j]);
}

// ---------------- GEMM: A (MxK bf16) @ BT (NxK bf16)^T, 128x128 tile, split-K=S ----------------
template<int S>
__global__ __launch_bounds__(256, 3)
void gemm_bt(const short* __restrict__ A, const short* __restrict__ BT,
             short* __restrict__ P0, short* __restrict__ P1, short* __restrict__ P2,
             int N, int K, int nx)
{
    __shared__ short As[128 * 64];
    __shared__ short Bs[128 * 64];
    // XCD swizzle (grid % 8 == 0); same-XCD neighbors get adjacent tiles of one K-slice
    const int nwg = gridDim.x;
    const int orig = blockIdx.x;
    const int wg = (orig & 7) * (nwg >> 3) + (orig >> 3);
    const int per = nwg / S;
    const int ks  = wg / per;
    const int bxy = wg - ks * per;
    const int bm = (bxy / nx) * 128, bn = (bxy % nx) * 128;
    const int kslice = ((K / S) + 63) & ~63;
    const int kbeg = ks * kslice;
    const int kend = (kbeg + kslice < K) ? (kbeg + kslice) : K;

    const int lane = threadIdx.x & 63;
    const int wid  = threadIdx.x >> 6;
    const int r = lane & 15, g = lane >> 4;
    const int wm = (wid >> 1) * 64, wn = (wid & 1) * 64;

    f32x4 acc[4][4];
    #pragma unroll
    for (int i = 0; i < 4; ++i)
        #pragma unroll
        for (int j = 0; j < 4; ++j) acc[i][j] = (f32x4){0.f, 0.f, 0.f, 0.f};

    const int srow = wid * 32 + (lane >> 3);
    const int scol = (lane & 7) * 8;

    for (int k0 = kbeg; k0 < kend; k0 += 64) {
        #pragma unroll
        for (int s2 = 0; s2 < 4; ++s2) {
            int row = srow + s2 * 8;
            int seg = wid * 4 + s2;
            load16_to_lds(A  + (size_t)(bm + row) * K + k0 + scol, As + seg * 512);
            load16_to_lds(BT + (size_t)(bn + row) * K + k0 + scol, Bs + seg * 512);
        }
        __syncthreads();
        #pragma unroll
        for (int kk = 0; kk < 64; kk += 32) {
            s8v a[4], b[4];
            #pragma unroll
            for (int t = 0; t < 4; ++t)
                a[t] = *(const s8v*)&As[(wm + t * 16 + r) * 64 + kk + g * 8];
            #pragma unroll
            for (int t = 0; t < 4; ++t)
                b[t] = *(const s8v*)&Bs[(wn + t * 16 + r) * 64 + kk + g * 8];
            __builtin_amdgcn_s_setprio(1);
            #pragma unroll
            for (int i = 0; i < 4; ++i)
                #pragma unroll
                for (int j = 0; j < 4; ++j)
                    acc[i][j] = mfma16(a[i], b[j], acc[i][j]);
            __builtin_amdgcn_s_setprio(0);
        }
        __syncthreads();
    }

    short* P = (ks == 0) ? P0 : ((ks == 1) ? P1 : P2);
    #pragma unroll
    for (int i = 0; i < 4; ++i)
        #pragma unroll
        for (int j = 0; j < 4; ++j)
            #pragma unroll
            for (int q = 0; q < 4; ++q) {
                int row = bm + wm + i * 16 + g * 4 + q;
                int col = bn + wn + j * 16 + r;
                P[(size_t)row * N + col] = f2bf_bits(acc[i][j][q]);
            }
}

// ---------------- epilogue: add split-K partials + RoPE -> qkv (Q,K cols 0..2559) ----------------
// Q columns (<2048) are additionally scaled by SCL (attention scale folded in).
__global__ void rope_add(const short* __restrict__ P0, const short* __restrict__ P1,
                         short* __restrict__ qkv,
                         const float* __restrict__ fc, const float* __restrict__ fs) {
    int idx = blockIdx.x * 256 + threadIdx.x;   // 2048 rows x 320 col-groups
    int row = idx / 320;
    int col = (idx - row * 320) * 8;
    s8v a = *(const s8v*)(P0 + (size_t)row * NQK + col);
    s8v b = *(const s8v*)(P1 + (size_t)row * NQK + col);
    int p0 = (col & 63) >> 1;
    float scl = (col < 2048) ? SCL : 1.0f;
    s8v o;
    #pragma unroll
    for (int k = 0; k < 4; ++k) {
        float xe = bfbits2f(a[2 * k])     + bfbits2f(b[2 * k]);
        float xo = bfbits2f(a[2 * k + 1]) + bfbits2f(b[2 * k + 1]);
        float c  = fc[row * 32 + p0 + k];
        float sn = fs[row * 32 + p0 + k];
        o[2 * k]     = f2bf_bits((xe * c - xo * sn) * scl);
        o[2 * k + 1] = f2bf_bits((xe * sn + xo * c) * scl);
    }
    *(s8v*)(qkv + (size_t)row * NQK + col) = o;
}

// ---------------- epilogue: add partials + transpose V -> vT[512][2048] ----------------
__global__ void vT_add(const short* __restrict__ P0, const short* __restrict__ P1,
                       short* __restrict__ vT) {
    __shared__ float tile[32][33];
    int bx = blockIdx.x * 32;   // V col block (0..511)
    int by = blockIdx.y * 32;   // row block (0..2047)
    int tx = threadIdx.x, ty = threadIdx.y;   // 32 x 8
    #pragma unroll
    for (int j = 0; j < 32; j += 8) {
        size_t off = (size_t)(by + ty + j) * NQK + 2560 + bx + tx;
        tile[ty + j][tx] = bfbits2f(P0[off]) + bfbits2f(P1[off]);
    }
    __syncthreads();
    #pragma unroll
    for (int j = 0; j < 32; j += 8)
        vT[(size_t)(bx + ty + j) * 2048 + by + tx] = f2bf_bits(tile[tx][ty + j]);
}

// ---------------- epilogue: add 3 partials -> fp32 out ----------------
__global__ void add_out3(const short* __restrict__ R0, const short* __restrict__ R1,
                         const short* __restrict__ R2, float* __restrict__ out) {
    int i = (blockIdx.x * 256 + threadIdx.x) * 8;
    s8v a = *(const s8v*)(R0 + i);
    s8v b = *(const s8v*)(R1 + i);
    s8v c = *(const s8v*)(R2 + i);
    #pragma unroll
    for (int k = 0; k < 8; k += 4) {
        float4 o;
        o.x = bfbits2f(a[k])     + bfbits2f(b[k])     + bfbits2f(c[k]);
        o.y = bfbits2f(a[k + 1]) + bfbits2f(b[k + 1]) + bfbits2f(c[k + 1]);
        o.z = bfbits2f(a[k + 2]) + bfbits2f(b[k + 2]) + bfbits2f(c[k + 2]);
        o.w = bfbits2f(a[k + 3]) + bfbits2f(b[k + 3]) + bfbits2f(c[k + 3]);
        *(float4*)(out + i + k) = o;
    }
}

// ---------------- flash attention: swapped QK^T -> lane-local softmax rows ----------------
// s[t][q] = S[kpos = t*16+g*4+q][qrow = r]; m/l are per-lane scalars (row r).
__global__ __launch_bounds__(256, 4)
void flash_attn(const short* __restrict__ qkv, const short* __restrict__ vT,
                short* __restrict__ O) {
    const int h  = blockIdx.x;                            // 0..31
    const int qi = (int)gridDim.y - 1 - (int)blockIdx.y;  // longest blocks first
    const int qb = qi * 64;
    const int kh = h >> 2;                                // GQA kv head
    const int lane = threadIdx.x & 63;
    const int wid  = threadIdx.x >> 6;
    const int r = lane & 15, g = lane >> 4;

    __shared__ short Ks[64][72];        // [kpos][d]
    __shared__ short Vt[64][72];        // [d][kpos]
    __shared__ short Pl[4][16][72];     // per-wave P [qrow][kpos^swz]

    s8v qf0, qf1;
    {
        const short* qrow = qkv + (size_t)(qb + wid * 16 + r) * NQK + h * 64;
        qf0 = *(const s8v*)(qrow + g * 8);
        qf1 = *(const s8v*)(qrow + 32 + g * 8);
    }

    float mrow = -1e30f, lrow = 0.f;
    f32x4 o[4];
    #pragma unroll
    for (int t = 0; t < 4; ++t) o[t] = (f32x4){0.f, 0.f, 0.f, 0.f};

    const int tr = threadIdx.x >> 2;
    const int tc = (threadIdx.x & 3) * 16;
    const int xm = (r & 3) << 3;        // P bank swizzle (col bits 3..4, self-inverse)

    const int nkt = qi + 1;
    for (int kt = 0; kt < nkt; ++kt) {
        { // stage K tile [kpos][d] and V^T tile [d][kpos]
            const short* kg = qkv + (size_t)(kt * 64 + tr) * NQK + 2048 + kh * 64 + tc;
            *(s8v*)&Ks[tr][tc]     = *(const s8v*)kg;
            *(s8v*)&Ks[tr][tc + 8] = *(const s8v*)(kg + 8);
            const short* vg = vT + (size_t)(kh * 64 + tr) * 2048 + kt * 64 + tc;
            *(s8v*)&Vt[tr][tc]     = *(const s8v*)vg;
            *(s8v*)&Vt[tr][tc + 8] = *(const s8v*)(vg + 8);
        }
        __syncthreads();

        // S^T = K @ Q^T  (swapped operands; same fragments, transposed output)
        f32x4 s[4];
        __builtin_amdgcn_s_setprio(1);
        #pragma unroll
        for (int t = 0; t < 4; ++t) {
            s8v ka0 = *(const s8v*)&Ks[t * 16 + r][g * 8];
            s8v ka1 = *(const s8v*)&Ks[t * 16 + r][32 + g * 8];
            f32x4 z = (f32x4){0.f, 0.f, 0.f, 0.f};
            z = mfma16(ka0, qf0, z);
            z = mfma16(ka1, qf1, z);
            s[t] = z;
        }
        __builtin_amdgcn_s_setprio(0);

        if (kt == nkt - 1) {   // diagonal tile: mask kpos > qrow
            const int qrow = qb + wid * 16 + r;
            #pragma unroll
            for (int t = 0; t < 4; ++t)
                #pragma unroll
                for (int q = 0; q < 4; ++q)
                    if (kt * 64 + t * 16 + g * 4 + q > qrow) s[t][q] = -1e30f;
        }

        // row max: in-lane tree + cross-g reduce (lanes r, r+16, r+32, r+48)
        float pm = fmaxf(fmaxf(fmaxf(s[0][0], s[0][1]), fmaxf(s[0][2], s[0][3])),
                         fmaxf(fmaxf(s[1][0], s[1][1]), fmaxf(s[1][2], s[1][3])));
        pm = fmaxf(pm, fmaxf(fmaxf(fmaxf(s[2][0], s[2][1]), fmaxf(s[2][2], s[2][3])),
                             fmaxf(fmaxf(s[3][0], s[3][1]), fmaxf(s[3][2], s[3][3]))));
        pm = fmaxf(pm, __shfl_xor(pm, 16, 64));
        pm = fmaxf(pm, __shfl_xor(pm, 32, 64));

        // defer-max: rescale only when max grew past threshold (log2 domain)
        if (__any(pm > mrow + 8.f)) {
            float mn = fmaxf(mrow, pm);
            float al = fexp2(mrow - mn);
            mrow = mn;
            lrow *= al;
            float alq[4];
            #pragma unroll
            for (int q = 0; q < 4; ++q) alq[q] = __shfl(al, g * 4 + q, 64);
            #pragma unroll
            for (int t = 0; t < 4; ++t)
                #pragma unroll
                for (int q = 0; q < 4; ++q) o[t][q] *= alq[q];
        }

        // p = exp2(s - m) (scalar m!), row sum, pack to Pl (4 x ds_write_b64)
        float rs = 0.f;
        #pragma unroll
        for (int t = 0; t < 4; ++t)
            #pragma unroll
            for (int q = 0; q < 4; ++q) {
                float p = fexp2(s[t][q] - mrow);
                s[t][q] = p;
                rs += p;
            }
        rs += __shfl_xor(rs, 16, 64);
        rs += __shfl_xor(rs, 32, 64);
        lrow += rs;

        #pragma unroll
        for (int t = 0; t < 4; ++t) {
            s4v pk;
            #pragma unroll
            for (int q = 0; q < 4; ++q) pk[q] = f2bf_bits(s[t][q]);
            *(s4v*)&Pl[wid][r][(t * 16 + g * 4) ^ xm] = pk;
        }
        asm volatile("s_waitcnt lgkmcnt(0)" ::: "memory");

        // O += P @ V
        s8v pa0 = *(const s8v*)&Pl[wid][r][(g * 8) ^ xm];
        s8v pa1 = *(const s8v*)&Pl[wid][r][32 + ((g * 8) ^ xm)];
        __builtin_amdgcn_s_setprio(1);
        #pragma unroll
        for (int t = 0; t < 4; ++t) {
            s8v vb0 = *(const s8v*)&Vt[t * 16 + r][g * 8];
            s8v vb1 = *(const s8v*)&Vt[t * 16 + r][32 + g * 8];
            o[t] = mfma16(pa0, vb0, o[t]);
            o[t] = mfma16(pa1, vb1, o[t]);
        }
        __builtin_amdgcn_s_setprio(0);
        __syncthreads();
    }

    // epilogue: O * (1/l), l broadcast from row-lanes to output layout
    float rl = __builtin_amdgcn_rcpf(lrow);
    float rlq[4];
    #pragma unroll
    for (int q = 0; q < 4; ++q) rlq[q] = __shfl(rl, g * 4 + q, 64);
    #pragma unroll
    for (int t = 0; t < 4; ++t)
        #pragma unroll
        for (int q = 0; q < 4; ++q)
            O[(size_t)(qb + wid * 16 + g * 4 + q) * 2048 + h * 64 + t * 16 + r] =
                f2bf_bits(o[t][q] * rlq[q]);
}

extern "C" void kernel_launch(void* const* d_in, const int* in_sizes, int n_in,
                              void* d_out, int out_size, void* d_ws, size_t ws_size,
                              hipStream_t stream)
{
    const float* x  = (const float*)d_in[0];
    const float* fc = (const float*)d_in[1];
    const float* fs = (const float*)d_in[2];
    // d_in[3] = mask (unused; causal applied analytically)
    const float* wq = (const float*)d_in[4];
    const float* wk = (const float*)d_in[5];
    const float* wv = (const float*)d_in[6];
    const float* wo = (const float*)d_in[7];
    float* out = (float*)d_out;

    char* ws = (char*)d_ws;
    short* xb    = (short*)(ws);                         //  8 MB: 2048x2048
    short* wqkvT = (short*)(ws + 8  * 1024 * 1024);      // 12 MB: 3072x2048
    short* woT   = (short*)(ws + 20 * 1024 * 1024);      //  8 MB: 2048x2048
    short* qkv   = (short*)(ws + 28 * 1024 * 1024);      // 12 MB: 2048x3072
    short* vT    = (short*)(ws + 40 * 1024 * 1024);      //  2 MB: 512x2048
    short* attnO = (short*)(ws + 42 * 1024 * 1024);      //  8 MB: 2048x2048
    short* P0    = (short*)(ws + 50 * 1024 * 1024);      // 13 MB partial
    short* P1    = (short*)(ws + 63 * 1024 * 1024);      // 13 MB partial
    short* P2o   = qkv;                                  // out-proj 3rd partial (qkv dead by then)

    dim3 tb(32, 8);
    cvt_f32_bf16<<<4096, 256, 0, stream>>>(x, xb);
    transpose_cvt<<<dim3(64, 64), tb, 0, stream>>>(wq, wqkvT, 2048);
    transpose_cvt<<<dim3(16, 64), tb, 0, stream>>>(wk, wqkvT + 2048 * 2048, 512);
    transpose_cvt<<<dim3(16, 64), tb, 0, stream>>>(wv, wqkvT + 2560 * 2048, 512);
    transpose_cvt<<<dim3(64, 64), tb, 0, stream>>>(wo, woT, 2048);

    // QKV projection, split-K=2: 24x16 tiles x 2 = 768 blocks
    gemm_bt<2><<<768, 256, 0, stream>>>(xb, wqkvT, P0, P1, nullptr, 3072, 2048, 24);
    rope_add<<<2560, 256, 0, stream>>>(P0, P1, qkv, fc, fs);
    vT_add<<<dim3(16, 64), tb, 0, stream>>>(P0, P1, vT);

    flash_attn<<<dim3(32, 32), 256, 0, stream>>>(qkv, vT, attnO);

    // out projection, split-K=3: 16x16 tiles x 3 = 768 blocks
    gemm_bt<3><<<768, 256, 0, stream>>>(attnO, woT, P0, P1, P2o, 2048, 2048, 16);
    add_out3<<<2048, 256, 0, stream>>>(P0, P1, P2o, out);
}

// Round 6
// 246.583 us; speedup vs baseline: 1.2199x; 1.0246x over previous
//
#include <hip/hip_runtime.h>
#include <hip/hip_bf16.h>

#define SEQ  2048
#define DIM  2048
#define NQK  3072   // q(2048) + k(512) + v(512) columns
#define NH   32
#define NKV  8
#define HD   64
#define SCL  0.18033688f   // 0.125 * log2(e), folded into Q at rope_add

typedef __attribute__((ext_vector_type(8))) short s8v;
typedef __attribute__((ext_vector_type(4))) short s4v;
typedef __attribute__((ext_vector_type(4))) float f32x4;

__device__ __forceinline__ short f2bf_bits(float f) {
    __hip_bfloat16 b = __float2bfloat16(f);
    short s; __builtin_memcpy(&s, &b, 2); return s;
}
__device__ __forceinline__ float bfbits2f(short s) {
    __hip_bfloat16 b; __builtin_memcpy(&b, &s, 2);
    return __bfloat162float(b);
}
__device__ __forceinline__ f32x4 mfma16(s8v a, s8v b, f32x4 c) {
    return __builtin_amdgcn_mfma_f32_16x16x32_bf16(a, b, c, 0, 0, 0);
}
__device__ __forceinline__ void load16_to_lds(const void* g, void* l) {
    __builtin_amdgcn_global_load_lds(
        (const __attribute__((address_space(1))) void*)g,
        (__attribute__((address_space(3))) void*)l, 16, 0, 0);
}
__device__ __forceinline__ float fexp2(float x) {
    float y; asm("v_exp_f32 %0, %1" : "=v"(y) : "v"(x)); return y;
}

// ---------------- convert x (fp32 -> bf16) ----------------
__global__ void cvt_f32_bf16(const float* __restrict__ src, short* __restrict__ dst) {
    int i = (blockIdx.x * 256 + threadIdx.x) * 4;
    float4 v = *(const float4*)(src + i);
    s4v o;
    o.x = f2bf_bits(v.x); o.y = f2bf_bits(v.y);
    o.z = f2bf_bits(v.z); o.w = f2bf_bits(v.w);
    *(s4v*)(dst + i) = o;
}

// ---------------- transpose + convert (K x Cs fp32 -> Cs x 2048 bf16) ----------------
__global__ void transpose_cvt(const float* __restrict__ src, short* __restrict__ dst, int Cs) {
    __shared__ float tile[32][33];
    int bx = blockIdx.x * 32, by = blockIdx.y * 32;
    int tx = threadIdx.x, ty = threadIdx.y;   // 32 x 8
    #pragma unroll
    for (int j = 0; j < 32; j += 8)
        tile[ty + j][tx] = src[(size_t)(by + ty + j) * Cs + bx + tx];
    __syncthreads();
    #pragma unroll
    for (int j = 0; j < 32; j += 8)
        dst[(size_t)(bx + ty + j) * 2048 + by + tx] = f2bf_bits(tile[tx][ty + j]);
}

// ---------------- GEMM: A (MxK bf16) @ BT (NxK bf16)^T, 128x128 tile, split-K=S ----------------
template<int S>
__global__ __launch_bounds__(256, 3)
void gemm_bt(const short* __restrict__ A, const short* __restrict__ BT,
             short* __restrict__ P0, short* __restrict__ P1, short* __restrict__ P2,
             int N, int K, int nx)
{
    __shared__ short As[128 * 64];
    __shared__ short Bs[128 * 64];
    const int nwg = gridDim.x;
    const int orig = blockIdx.x;
    const int wg = (orig & 7) * (nwg >> 3) + (orig >> 3);
    const int per = nwg / S;
    const int ks  = wg / per;
    const int bxy = wg - ks * per;
    const int bm = (bxy / nx) * 128, bn = (bxy % nx) * 128;
    const int kslice = ((K / S) + 63) & ~63;
    const int kbeg = ks * kslice;
    const int kend = (kbeg + kslice < K) ? (kbeg + kslice) : K;

    const int lane = threadIdx.x & 63;
    const int wid  = threadIdx.x >> 6;
    const int r = lane & 15, g = lane >> 4;
    const int wm = (wid >> 1) * 64, wn = (wid & 1) * 64;

    f32x4 acc[4][4];
    #pragma unroll
    for (int i = 0; i < 4; ++i)
        #pragma unroll
        for (int j = 0; j < 4; ++j) acc[i][j] = (f32x4){0.f, 0.f, 0.f, 0.f};

    const int srow = wid * 32 + (lane >> 3);
    const int scol = (lane & 7) * 8;

    for (int k0 = kbeg; k0 < kend; k0 += 64) {
        #pragma unroll
        for (int s2 = 0; s2 < 4; ++s2) {
            int row = srow + s2 * 8;
            int seg = wid * 4 + s2;
            load16_to_lds(A  + (size_t)(bm + row) * K + k0 + scol, As + seg * 512);
            load16_to_lds(BT + (size_t)(bn + row) * K + k0 + scol, Bs + seg * 512);
        }
        __syncthreads();
        #pragma unroll
        for (int kk = 0; kk < 64; kk += 32) {
            s8v a[4], b[4];
            #pragma unroll
            for (int t = 0; t < 4; ++t)
                a[t] = *(const s8v*)&As[(wm + t * 16 + r) * 64 + kk + g * 8];
            #pragma unroll
            for (int t = 0; t < 4; ++t)
                b[t] = *(const s8v*)&Bs[(wn + t * 16 + r) * 64 + kk + g * 8];
            __builtin_amdgcn_s_setprio(1);
            #pragma unroll
            for (int i = 0; i < 4; ++i)
                #pragma unroll
                for (int j = 0; j < 4; ++j)
                    acc[i][j] = mfma16(a[i], b[j], acc[i][j]);
            __builtin_amdgcn_s_setprio(0);
        }
        __syncthreads();
    }

    short* P = (ks == 0) ? P0 : ((ks == 1) ? P1 : P2);
    #pragma unroll
    for (int i = 0; i < 4; ++i)
        #pragma unroll
        for (int j = 0; j < 4; ++j)
            #pragma unroll
            for (int q = 0; q < 4; ++q) {
                int row = bm + wm + i * 16 + g * 4 + q;
                int col = bn + wn + j * 16 + r;
                P[(size_t)row * N + col] = f2bf_bits(acc[i][j][q]);
            }
}

// ---------------- epilogue: add split-K partials + RoPE -> qkv (Q,K cols 0..2559) ----------------
__global__ void rope_add(const short* __restrict__ P0, const short* __restrict__ P1,
                         short* __restrict__ qkv,
                         const float* __restrict__ fc, const float* __restrict__ fs) {
    int idx = blockIdx.x * 256 + threadIdx.x;   // 2048 rows x 320 col-groups
    int row = idx / 320;
    int col = (idx - row * 320) * 8;
    s8v a = *(const s8v*)(P0 + (size_t)row * NQK + col);
    s8v b = *(const s8v*)(P1 + (size_t)row * NQK + col);
    int p0 = (col & 63) >> 1;
    float scl = (col < 2048) ? SCL : 1.0f;
    s8v o;
    #pragma unroll
    for (int k = 0; k < 4; ++k) {
        float xe = bfbits2f(a[2 * k])     + bfbits2f(b[2 * k]);
        float xo = bfbits2f(a[2 * k + 1]) + bfbits2f(b[2 * k + 1]);
        float c  = fc[row * 32 + p0 + k];
        float sn = fs[row * 32 + p0 + k];
        o[2 * k]     = f2bf_bits((xe * c - xo * sn) * scl);
        o[2 * k + 1] = f2bf_bits((xe * sn + xo * c) * scl);
    }
    *(s8v*)(qkv + (size_t)row * NQK + col) = o;
}

// ---------------- epilogue: add partials + transpose V -> vT[512][2048] ----------------
__global__ void vT_add(const short* __restrict__ P0, const short* __restrict__ P1,
                       short* __restrict__ vT) {
    __shared__ float tile[32][33];
    int bx = blockIdx.x * 32;   // V col block (0..511)
    int by = blockIdx.y * 32;   // row block (0..2047)
    int tx = threadIdx.x, ty = threadIdx.y;   // 32 x 8
    #pragma unroll
    for (int j = 0; j < 32; j += 8) {
        size_t off = (size_t)(by + ty + j) * NQK + 2560 + bx + tx;
        tile[ty + j][tx] = bfbits2f(P0[off]) + bfbits2f(P1[off]);
    }
    __syncthreads();
    #pragma unroll
    for (int j = 0; j < 32; j += 8)
        vT[(size_t)(bx + ty + j) * 2048 + by + tx] = f2bf_bits(tile[tx][ty + j]);
}

// ---------------- epilogue: add 3 partials -> fp32 out ----------------
__global__ void add_out3(const short* __restrict__ R0, const short* __restrict__ R1,
                         const short* __restrict__ R2, float* __restrict__ out) {
    int i = (blockIdx.x * 256 + threadIdx.x) * 8;
    s8v a = *(const s8v*)(R0 + i);
    s8v b = *(const s8v*)(R1 + i);
    s8v c = *(const s8v*)(R2 + i);
    #pragma unroll
    for (int k = 0; k < 8; k += 4) {
        float4 o;
        o.x = bfbits2f(a[k])     + bfbits2f(b[k])     + bfbits2f(c[k]);
        o.y = bfbits2f(a[k + 1]) + bfbits2f(b[k + 1]) + bfbits2f(c[k + 1]);
        o.z = bfbits2f(a[k + 2]) + bfbits2f(b[k + 2]) + bfbits2f(c[k + 2]);
        o.w = bfbits2f(a[k + 3]) + bfbits2f(b[k + 3]) + bfbits2f(c[k + 3]);
        *(float4*)(out + i + k) = o;
    }
}

// ---------------- flash attention: swapped QK^T, lane-local softmax, T14 async staging ----------------
// s[t][q] = S[qrow = r][kpos = t*16 + g*4 + q]; m/l are per-lane scalars (row r).
__global__ __launch_bounds__(256, 5)
void flash_attn(const short* __restrict__ qkv, const short* __restrict__ vT,
                short* __restrict__ O) {
    const int h  = blockIdx.x;                            // 0..31
    const int qi = (int)gridDim.y - 1 - (int)blockIdx.y;  // longest blocks first
    const int qb = qi * 64;
    const int kh = h >> 2;                                // GQA kv head
    const int lane = threadIdx.x & 63;
    const int wid  = threadIdx.x >> 6;
    const int r = lane & 15, g = lane >> 4;

    __shared__ short Ks[64][72];        // [kpos][d]
    __shared__ short Vt[64][72];        // [d][kpos]
    __shared__ short Pl[4][16][72];     // per-wave P [qrow][kpos] (no swizzle: write 2-way, read at b128 floor)

    s8v qf0, qf1;
    {
        const short* qrow = qkv + (size_t)(qb + wid * 16 + r) * NQK + h * 64;
        qf0 = *(const s8v*)(qrow + g * 8);
        qf1 = *(const s8v*)(qrow + 32 + g * 8);
    }

    float mrow = -1e30f, lrow = 0.f;
    f32x4 o[4];
    #pragma unroll
    for (int t = 0; t < 4; ++t) o[t] = (f32x4){0.f, 0.f, 0.f, 0.f};

    const int tr = threadIdx.x >> 2;
    const int tc = (threadIdx.x & 3) * 16;

    // prologue: stage tile 0
    {
        const short* kg = qkv + (size_t)(tr) * NQK + 2048 + kh * 64 + tc;
        *(s8v*)&Ks[tr][tc]     = *(const s8v*)kg;
        *(s8v*)&Ks[tr][tc + 8] = *(const s8v*)(kg + 8);
        const short* vg = vT + (size_t)(kh * 64 + tr) * 2048 + tc;
        *(s8v*)&Vt[tr][tc]     = *(const s8v*)vg;
        *(s8v*)&Vt[tr][tc + 8] = *(const s8v*)(vg + 8);
    }
    __syncthreads();

    const int nkt = qi + 1;
    for (int kt = 0; kt < nkt; ++kt) {
        const bool more = (kt + 1 < nkt);
        // T14: issue next tile's global loads now; consumed after the post-PV barrier
        s8v kn0, kn1, vn0, vn1;
        if (more) {
            const short* kg = qkv + (size_t)((kt + 1) * 64 + tr) * NQK + 2048 + kh * 64 + tc;
            kn0 = *(const s8v*)kg;
            kn1 = *(const s8v*)(kg + 8);
            const short* vg = vT + (size_t)(kh * 64 + tr) * 2048 + (kt + 1) * 64 + tc;
            vn0 = *(const s8v*)vg;
            vn1 = *(const s8v*)(vg + 8);
        }

        // S^T = K @ Q^T  (swapped operands; same fragments, transposed output)
        f32x4 s[4];
        __builtin_amdgcn_s_setprio(1);
        #pragma unroll
        for (int t = 0; t < 4; ++t) {
            s8v ka0 = *(const s8v*)&Ks[t * 16 + r][g * 8];
            s8v ka1 = *(const s8v*)&Ks[t * 16 + r][32 + g * 8];
            f32x4 z = (f32x4){0.f, 0.f, 0.f, 0.f};
            z = mfma16(ka0, qf0, z);
            z = mfma16(ka1, qf1, z);
            s[t] = z;
        }
        __builtin_amdgcn_s_setprio(0);

        if (kt == nkt - 1) {   // diagonal tile: mask kpos > qrow
            const int qrow = qb + wid * 16 + r;
            #pragma unroll
            for (int t = 0; t < 4; ++t)
                #pragma unroll
                for (int q = 0; q < 4; ++q)
                    if (kt * 64 + t * 16 + g * 4 + q > qrow) s[t][q] = -1e30f;
        }

        // row max: in-lane tree + cross-g reduce
        float pm = fmaxf(fmaxf(fmaxf(s[0][0], s[0][1]), fmaxf(s[0][2], s[0][3])),
                         fmaxf(fmaxf(s[1][0], s[1][1]), fmaxf(s[1][2], s[1][3])));
        pm = fmaxf(pm, fmaxf(fmaxf(fmaxf(s[2][0], s[2][1]), fmaxf(s[2][2], s[2][3])),
                             fmaxf(fmaxf(s[3][0], s[3][1]), fmaxf(s[3][2], s[3][3]))));
        pm = fmaxf(pm, __shfl_xor(pm, 16, 64));
        pm = fmaxf(pm, __shfl_xor(pm, 32, 64));

        // defer-max: rescale only when max grew past threshold (log2 domain)
        if (__any(pm > mrow + 8.f)) {
            float mn = fmaxf(mrow, pm);
            float al = fexp2(mrow - mn);
            mrow = mn;
            lrow *= al;
            float alq[4];
            #pragma unroll
            for (int q = 0; q < 4; ++q) alq[q] = __shfl(al, g * 4 + q, 64);
            #pragma unroll
            for (int t = 0; t < 4; ++t)
                #pragma unroll
                for (int q = 0; q < 4; ++q) o[t][q] *= alq[q];
        }

        // p = exp2(s - m) (scalar m), row sum, pack to Pl (4 x ds_write_b64, 2-way = free)
        float rs = 0.f;
        #pragma unroll
        for (int t = 0; t < 4; ++t)
            #pragma unroll
            for (int q = 0; q < 4; ++q) {
                float p = fexp2(s[t][q] - mrow);
                s[t][q] = p;
                rs += p;
            }
        rs += __shfl_xor(rs, 16, 64);
        rs += __shfl_xor(rs, 32, 64);
        lrow += rs;

        #pragma unroll
        for (int t = 0; t < 4; ++t) {
            s4v pk;
            #pragma unroll
            for (int q = 0; q < 4; ++q) pk[q] = f2bf_bits(s[t][q]);
            *(s4v*)&Pl[wid][r][t * 16 + g * 4] = pk;
        }
        asm volatile("s_waitcnt lgkmcnt(0)" ::: "memory");

        // O += P @ V
        s8v pa0 = *(const s8v*)&Pl[wid][r][g * 8];
        s8v pa1 = *(const s8v*)&Pl[wid][r][32 + g * 8];
        __builtin_amdgcn_s_setprio(1);
        #pragma unroll
        for (int t = 0; t < 4; ++t) {
            s8v vb0 = *(const s8v*)&Vt[t * 16 + r][g * 8];
            s8v vb1 = *(const s8v*)&Vt[t * 16 + r][32 + g * 8];
            o[t] = mfma16(pa0, vb0, o[t]);
            o[t] = mfma16(pa1, vb1, o[t]);
        }
        __builtin_amdgcn_s_setprio(0);
        __syncthreads();          // everyone done reading Ks/Vt for kt

        if (more) {               // write prefetched tile, one barrier before next compute
            *(s8v*)&Ks[tr][tc]     = kn0;
            *(s8v*)&Ks[tr][tc + 8] = kn1;
            *(s8v*)&Vt[tr][tc]     = vn0;
            *(s8v*)&Vt[tr][tc + 8] = vn1;
            __syncthreads();
        }
    }

    // epilogue: O * (1/l), l broadcast from row-lanes to output layout
    float rl = __builtin_amdgcn_rcpf(lrow);
    float rlq[4];
    #pragma unroll
    for (int q = 0; q < 4; ++q) rlq[q] = __shfl(rl, g * 4 + q, 64);
    #pragma unroll
    for (int t = 0; t < 4; ++t)
        #pragma unroll
        for (int q = 0; q < 4; ++q)
            O[(size_t)(qb + wid * 16 + g * 4 + q) * 2048 + h * 64 + t * 16 + r] =
                f2bf_bits(o[t][q] * rlq[q]);
}

extern "C" void kernel_launch(void* const* d_in, const int* in_sizes, int n_in,
                              void* d_out, int out_size, void* d_ws, size_t ws_size,
                              hipStream_t stream)
{
    const float* x  = (const float*)d_in[0];
    const float* fc = (const float*)d_in[1];
    const float* fs = (const float*)d_in[2];
    // d_in[3] = mask (unused; causal applied analytically)
    const float* wq = (const float*)d_in[4];
    const float* wk = (const float*)d_in[5];
    const float* wv = (const float*)d_in[6];
    const float* wo = (const float*)d_in[7];
    float* out = (float*)d_out;

    char* ws = (char*)d_ws;
    short* xb    = (short*)(ws);                         //  8 MB: 2048x2048
    short* wqkvT = (short*)(ws + 8  * 1024 * 1024);      // 12 MB: 3072x2048
    short* woT   = (short*)(ws + 20 * 1024 * 1024);      //  8 MB: 2048x2048
    short* qkv   = (short*)(ws + 28 * 1024 * 1024);      // 12 MB: 2048x3072
    short* vT    = (short*)(ws + 40 * 1024 * 1024);      //  2 MB: 512x2048
    short* attnO = (short*)(ws + 42 * 1024 * 1024);      //  8 MB: 2048x2048
    short* P0    = (short*)(ws + 50 * 1024 * 1024);      // 13 MB partial
    short* P1    = (short*)(ws + 63 * 1024 * 1024);      // 13 MB partial
    short* P2o   = qkv;                                  // out-proj 3rd partial (qkv dead by then)

    dim3 tb(32, 8);
    cvt_f32_bf16<<<4096, 256, 0, stream>>>(x, xb);
    transpose_cvt<<<dim3(64, 64), tb, 0, stream>>>(wq, wqkvT, 2048);
    transpose_cvt<<<dim3(16, 64), tb, 0, stream>>>(wk, wqkvT + 2048 * 2048, 512);
    transpose_cvt<<<dim3(16, 64), tb, 0, stream>>>(wv, wqkvT + 2560 * 2048, 512);
    transpose_cvt<<<dim3(64, 64), tb, 0, stream>>>(wo, woT, 2048);

    // QKV projection, split-K=2: 24x16 tiles x 2 = 768 blocks
    gemm_bt<2><<<768, 256, 0, stream>>>(xb, wqkvT, P0, P1, nullptr, 3072, 2048, 24);
    rope_add<<<2560, 256, 0, stream>>>(P0, P1, qkv, fc, fs);
    vT_add<<<dim3(16, 64), tb, 0, stream>>>(P0, P1, vT);

    flash_attn<<<dim3(32, 32), 256, 0, stream>>>(qkv, vT, attnO);

    // out projection, split-K=3: 16x16 tiles x 3 = 768 blocks
    gemm_bt<3><<<768, 256, 0, stream>>>(attnO, woT, P0, P1, P2o, 2048, 2048, 16);
    add_out3<<<2048, 256, 0, stream>>>(P0, P1, P2o, out);
}

// Round 7
// 235.823 us; speedup vs baseline: 1.2756x; 1.0456x over previous
//
#include <hip/hip_runtime.h>
#include <hip/hip_bf16.h>

#define SEQ  2048
#define DIM  2048
#define NQK  3072   // q(2048) + k(512) + v(512) columns
#define NH   32
#define NKV  8
#define HD   64
#define SCL  0.18033688f   // 0.125 * log2(e), folded into Q at rope/ep1

typedef __attribute__((ext_vector_type(8))) short s8v;
typedef __attribute__((ext_vector_type(4))) short s4v;
typedef __attribute__((ext_vector_type(4))) float f32x4;

__device__ __forceinline__ short f2bf_bits(float f) {
    __hip_bfloat16 b = __float2bfloat16(f);
    short s; __builtin_memcpy(&s, &b, 2); return s;
}
__device__ __forceinline__ float bfbits2f(short s) {
    __hip_bfloat16 b; __builtin_memcpy(&b, &s, 2);
    return __bfloat162float(b);
}
__device__ __forceinline__ f32x4 mfma16(s8v a, s8v b, f32x4 c) {
    return __builtin_amdgcn_mfma_f32_16x16x32_bf16(a, b, c, 0, 0, 0);
}
__device__ __forceinline__ void load16_to_lds(const void* g, void* l) {
    __builtin_amdgcn_global_load_lds(
        (const __attribute__((address_space(1))) void*)g,
        (__attribute__((address_space(3))) void*)l, 16, 0, 0);
}
__device__ __forceinline__ float fexp2(float x) {
    float y; asm("v_exp_f32 %0, %1" : "=v"(y) : "v"(x)); return y;
}

// ---------------- prep: x cvt (blocks 0..4095) + 4 weight transposes (blocks 4096..14335) ----------------
__global__ void prep(const float* __restrict__ x,
                     const float* __restrict__ wq, const float* __restrict__ wk,
                     const float* __restrict__ wv, const float* __restrict__ wo,
                     short* __restrict__ xb, short* __restrict__ wqkvT, short* __restrict__ woT)
{
    __shared__ float tile[32][33];
    int b = blockIdx.x;
    int tid = threadIdx.x;
    if (b < 4096) {                      // cvt x -> bf16
        int i = (b * 256 + tid) * 4;
        float4 v = *(const float4*)(x + i);
        s4v o;
        o.x = f2bf_bits(v.x); o.y = f2bf_bits(v.y);
        o.z = f2bf_bits(v.z); o.w = f2bf_bits(v.w);
        *(s4v*)(xb + i) = o;
        return;
    }
    b -= 4096;
    const float* src; short* dst; int Cs, bx, by;
    if (b < 4096)      {             src = wq; dst = wqkvT;              Cs = 2048; bx = (b & 63) * 32; by = (b >> 6) * 32; }
    else if (b < 5120) { int j = b - 4096; src = wk; dst = wqkvT + 2048 * 2048; Cs = 512; bx = (j & 15) * 32; by = (j >> 4) * 32; }
    else if (b < 6144) { int j = b - 5120; src = wv; dst = wqkvT + 2560 * 2048; Cs = 512; bx = (j & 15) * 32; by = (j >> 4) * 32; }
    else               { int j = b - 6144; src = wo; dst = woT;               Cs = 2048; bx = (j & 63) * 32; by = (j >> 6) * 32; }
    int tx = tid & 31, ty = tid >> 5;    // 32 x 8
    #pragma unroll
    for (int j = 0; j < 32; j += 8)
        tile[ty + j][tx] = src[(size_t)(by + ty + j) * Cs + bx + tx];
    __syncthreads();
    #pragma unroll
    for (int j = 0; j < 32; j += 8)
        dst[(size_t)(bx + ty + j) * 2048 + by + tx] = f2bf_bits(tile[tx][ty + j]);
}

// ---------------- GEMM: A (MxK bf16) @ BT (NxK bf16)^T, 128x128 tile, split-K=S ----------------
template<int S>
__global__ __launch_bounds__(256, 3)
void gemm_bt(const short* __restrict__ A, const short* __restrict__ BT,
             short* __restrict__ P0, short* __restrict__ P1,
             short* __restrict__ P2, short* __restrict__ P3,
             int N, int K, int nx)
{
    __shared__ short As[128 * 64];
    __shared__ short Bs[128 * 64];
    const int nwg = gridDim.x;
    const int orig = blockIdx.x;
    const int wg = (orig & 7) * (nwg >> 3) + (orig >> 3);
    const int per = nwg / S;
    const int ks  = wg / per;
    const int bxy = wg - ks * per;
    const int bm = (bxy / nx) * 128, bn = (bxy % nx) * 128;
    const int kslice = K / S;
    const int kbeg = ks * kslice, kend = kbeg + kslice;

    const int lane = threadIdx.x & 63;
    const int wid  = threadIdx.x >> 6;
    const int r = lane & 15, g = lane >> 4;
    const int wm = (wid >> 1) * 64, wn = (wid & 1) * 64;

    f32x4 acc[4][4];
    #pragma unroll
    for (int i = 0; i < 4; ++i)
        #pragma unroll
        for (int j = 0; j < 4; ++j) acc[i][j] = (f32x4){0.f, 0.f, 0.f, 0.f};

    const int srow = wid * 32 + (lane >> 3);
    const int scol = (lane & 7) * 8;

    for (int k0 = kbeg; k0 < kend; k0 += 64) {
        #pragma unroll
        for (int s2 = 0; s2 < 4; ++s2) {
            int row = srow + s2 * 8;
            int seg = wid * 4 + s2;
            load16_to_lds(A  + (size_t)(bm + row) * K + k0 + scol, As + seg * 512);
            load16_to_lds(BT + (size_t)(bn + row) * K + k0 + scol, Bs + seg * 512);
        }
        __syncthreads();
        #pragma unroll
        for (int kk = 0; kk < 64; kk += 32) {
            s8v a[4], b[4];
            #pragma unroll
            for (int t = 0; t < 4; ++t)
                a[t] = *(const s8v*)&As[(wm + t * 16 + r) * 64 + kk + g * 8];
            #pragma unroll
            for (int t = 0; t < 4; ++t)
                b[t] = *(const s8v*)&Bs[(wn + t * 16 + r) * 64 + kk + g * 8];
            __builtin_amdgcn_s_setprio(1);
            #pragma unroll
            for (int i = 0; i < 4; ++i)
                #pragma unroll
                for (int j = 0; j < 4; ++j)
                    acc[i][j] = mfma16(a[i], b[j], acc[i][j]);
            __builtin_amdgcn_s_setprio(0);
        }
        __syncthreads();
    }

    short* P = P0;
    if (S >= 2 && ks == 1) P = P1;
    if (S >= 3 && ks == 2) P = P2;
    if (S >= 4 && ks == 3) P = P3;
    #pragma unroll
    for (int i = 0; i < 4; ++i)
        #pragma unroll
        for (int j = 0; j < 4; ++j)
            #pragma unroll
            for (int q = 0; q < 4; ++q) {
                int row = bm + wm + i * 16 + g * 4 + q;
                int col = bn + wn + j * 16 + r;
                P[(size_t)row * N + col] = f2bf_bits(acc[i][j][q]);
            }
}

// ---------------- ep1: add 2 partials + RoPE -> qkv (blocks 0..2559) ; V transpose -> vT (2560..3583) ----------------
__global__ void ep1(const short* __restrict__ P0, const short* __restrict__ P1,
                    short* __restrict__ qkv, short* __restrict__ vT,
                    const float* __restrict__ fc, const float* __restrict__ fs)
{
    __shared__ float tile[32][33];
    int b = blockIdx.x;
    int tid = threadIdx.x;
    if (b < 2560) {                       // rope + add on Q/K columns
        int idx = b * 256 + tid;          // 2048 rows x 320 col-groups
        int row = idx / 320;
        int col = (idx - row * 320) * 8;
        s8v a = *(const s8v*)(P0 + (size_t)row * NQK + col);
        s8v bb = *(const s8v*)(P1 + (size_t)row * NQK + col);
        int p0 = (col & 63) >> 1;
        float scl = (col < 2048) ? SCL : 1.0f;
        s8v o;
        #pragma unroll
        for (int k = 0; k < 4; ++k) {
            float xe = bfbits2f(a[2 * k])     + bfbits2f(bb[2 * k]);
            float xo = bfbits2f(a[2 * k + 1]) + bfbits2f(bb[2 * k + 1]);
            float c  = fc[row * 32 + p0 + k];
            float sn = fs[row * 32 + p0 + k];
            o[2 * k]     = f2bf_bits((xe * c - xo * sn) * scl);
            o[2 * k + 1] = f2bf_bits((xe * sn + xo * c) * scl);
        }
        *(s8v*)(qkv + (size_t)row * NQK + col) = o;
        return;
    }
    {                                     // V add + transpose
        int j = b - 2560;                 // 16 x 64 tiles
        int bx = (j & 15) * 32, by = (j >> 4) * 32;
        int tx = tid & 31, ty = tid >> 5;
        #pragma unroll
        for (int jj = 0; jj < 32; jj += 8) {
            size_t off = (size_t)(by + ty + jj) * NQK + 2560 + bx + tx;
            tile[ty + jj][tx] = bfbits2f(P0[off]) + bfbits2f(P1[off]);
        }
        __syncthreads();
        #pragma unroll
        for (int jj = 0; jj < 32; jj += 8)
            vT[(size_t)(bx + ty + jj) * 2048 + by + tx] = f2bf_bits(tile[tx][ty + jj]);
    }
}

// ---------------- epilogue: add 4 partials -> fp32 out ----------------
__global__ void add_out4(const short* __restrict__ R0, const short* __restrict__ R1,
                         const short* __restrict__ R2, const short* __restrict__ R3,
                         float* __restrict__ out) {
    int i = (blockIdx.x * 256 + threadIdx.x) * 8;
    s8v a = *(const s8v*)(R0 + i);
    s8v b = *(const s8v*)(R1 + i);
    s8v c = *(const s8v*)(R2 + i);
    s8v d = *(const s8v*)(R3 + i);
    #pragma unroll
    for (int k = 0; k < 8; k += 4) {
        float4 o;
        o.x = (bfbits2f(a[k])     + bfbits2f(b[k]))     + (bfbits2f(c[k])     + bfbits2f(d[k]));
        o.y = (bfbits2f(a[k + 1]) + bfbits2f(b[k + 1])) + (bfbits2f(c[k + 1]) + bfbits2f(d[k + 1]));
        o.z = (bfbits2f(a[k + 2]) + bfbits2f(b[k + 2])) + (bfbits2f(c[k + 2]) + bfbits2f(d[k + 2]));
        o.w = (bfbits2f(a[k + 3]) + bfbits2f(b[k + 3])) + (bfbits2f(c[k + 3]) + bfbits2f(d[k + 3]));
        *(float4*)(out + i + k) = o;
    }
}

// ---------------- flash attention: swapped QK^T, lane-local softmax, T14 + dbuf (1 barrier/tile) ----------------
// s[t][q] = S[qrow = r][kpos = t*16 + g*4 + q]; m/l are per-lane scalars (row r).
__global__ __launch_bounds__(256, 3)
void flash_attn(const short* __restrict__ qkv, const short* __restrict__ vT,
                short* __restrict__ O) {
    const int h  = blockIdx.x;                            // 0..31
    const int qi = (int)gridDim.y - 1 - (int)blockIdx.y;  // longest blocks first
    const int qb = qi * 64;
    const int kh = h >> 2;                                // GQA kv head
    const int lane = threadIdx.x & 63;
    const int wid  = threadIdx.x >> 6;
    const int r = lane & 15, g = lane >> 4;

    __shared__ short Ks[2][64][72];     // [buf][kpos][d]
    __shared__ short Vt[2][64][72];     // [buf][d][kpos]
    __shared__ short Pl[4][16][72];     // per-wave P [qrow][kpos]

    s8v qf0, qf1;
    {
        const short* qrow = qkv + (size_t)(qb + wid * 16 + r) * NQK + h * 64;
        qf0 = *(const s8v*)(qrow + g * 8);
        qf1 = *(const s8v*)(qrow + 32 + g * 8);
    }

    float mrow = -1e30f, lrow = 0.f;
    f32x4 o[4];
    #pragma unroll
    for (int t = 0; t < 4; ++t) o[t] = (f32x4){0.f, 0.f, 0.f, 0.f};

    const int tr = threadIdx.x >> 2;
    const int tc = (threadIdx.x & 3) * 16;

    // prologue: stage tile 0 into buf 0
    {
        const short* kg = qkv + (size_t)tr * NQK + 2048 + kh * 64 + tc;
        *(s8v*)&Ks[0][tr][tc]     = *(const s8v*)kg;
        *(s8v*)&Ks[0][tr][tc + 8] = *(const s8v*)(kg + 8);
        const short* vg = vT + (size_t)(kh * 64 + tr) * 2048 + tc;
        *(s8v*)&Vt[0][tr][tc]     = *(const s8v*)vg;
        *(s8v*)&Vt[0][tr][tc + 8] = *(const s8v*)(vg + 8);
    }
    __syncthreads();

    const int nkt = qi + 1;
    for (int kt = 0; kt < nkt; ++kt) {
        const int cur = kt & 1;
        const bool more = (kt + 1 < nkt);
        // T14: issue next tile's global loads now; LDS-written into buf^1 before PV
        s8v kn0, kn1, vn0, vn1;
        if (more) {
            const short* kg = qkv + (size_t)((kt + 1) * 64 + tr) * NQK + 2048 + kh * 64 + tc;
            kn0 = *(const s8v*)kg;
            kn1 = *(const s8v*)(kg + 8);
            const short* vg = vT + (size_t)(kh * 64 + tr) * 2048 + (kt + 1) * 64 + tc;
            vn0 = *(const s8v*)vg;
            vn1 = *(const s8v*)(vg + 8);
        }

        // S^T = K @ Q^T  (swapped operands; same fragments, transposed output)
        f32x4 s[4];
        __builtin_amdgcn_s_setprio(1);
        #pragma unroll
        for (int t = 0; t < 4; ++t) {
            s8v ka0 = *(const s8v*)&Ks[cur][t * 16 + r][g * 8];
            s8v ka1 = *(const s8v*)&Ks[cur][t * 16 + r][32 + g * 8];
            f32x4 z = (f32x4){0.f, 0.f, 0.f, 0.f};
            z = mfma16(ka0, qf0, z);
            z = mfma16(ka1, qf1, z);
            s[t] = z;
        }
        __builtin_amdgcn_s_setprio(0);

        if (kt == nkt - 1) {   // diagonal tile: mask kpos > qrow
            const int qrow = qb + wid * 16 + r;
            #pragma unroll
            for (int t = 0; t < 4; ++t)
                #pragma unroll
                for (int q = 0; q < 4; ++q)
                    if (kt * 64 + t * 16 + g * 4 + q > qrow) s[t][q] = -1e30f;
        }

        // row max: in-lane tree + cross-g reduce
        float pm = fmaxf(fmaxf(fmaxf(s[0][0], s[0][1]), fmaxf(s[0][2], s[0][3])),
                         fmaxf(fmaxf(s[1][0], s[1][1]), fmaxf(s[1][2], s[1][3])));
        pm = fmaxf(pm, fmaxf(fmaxf(fmaxf(s[2][0], s[2][1]), fmaxf(s[2][2], s[2][3])),
                             fmaxf(fmaxf(s[3][0], s[3][1]), fmaxf(s[3][2], s[3][3]))));
        pm = fmaxf(pm, __shfl_xor(pm, 16, 64));
        pm = fmaxf(pm, __shfl_xor(pm, 32, 64));

        // defer-max: rescale only when max grew past threshold (log2 domain)
        if (__any(pm > mrow + 8.f)) {
            float mn = fmaxf(mrow, pm);
            float al = fexp2(mrow - mn);
            mrow = mn;
            lrow *= al;
            float alq[4];
            #pragma unroll
            for (int q = 0; q < 4; ++q) alq[q] = __shfl(al, g * 4 + q, 64);
            #pragma unroll
            for (int t = 0; t < 4; ++t)
                #pragma unroll
                for (int q = 0; q < 4; ++q) o[t][q] *= alq[q];
        }

        // p = exp2(s - m) (scalar m), row sum, pack to Pl
        float rs = 0.f;
        #pragma unroll
        for (int t = 0; t < 4; ++t)
            #pragma unroll
            for (int q = 0; q < 4; ++q) {
                float p = fexp2(s[t][q] - mrow);
                s[t][q] = p;
                rs += p;
            }
        rs += __shfl_xor(rs, 16, 64);
        rs += __shfl_xor(rs, 32, 64);
        lrow += rs;

        #pragma unroll
        for (int t = 0; t < 4; ++t) {
            s4v pk;
            #pragma unroll
            for (int q = 0; q < 4; ++q) pk[q] = f2bf_bits(s[t][q]);
            *(s4v*)&Pl[wid][r][t * 16 + g * 4] = pk;
        }

        // write prefetched tile into buf^1 (hidden under PV); safe: buf^1 last read in iter kt-1
        if (more) {
            *(s8v*)&Ks[cur ^ 1][tr][tc]     = kn0;
            *(s8v*)&Ks[cur ^ 1][tr][tc + 8] = kn1;
            *(s8v*)&Vt[cur ^ 1][tr][tc]     = vn0;
            *(s8v*)&Vt[cur ^ 1][tr][tc + 8] = vn1;
        }
        asm volatile("s_waitcnt lgkmcnt(0)" ::: "memory");

        // O += P @ V
        s8v pa0 = *(const s8v*)&Pl[wid][r][g * 8];
        s8v pa1 = *(const s8v*)&Pl[wid][r][32 + g * 8];
        __builtin_amdgcn_s_setprio(1);
        #pragma unroll
        for (int t = 0; t < 4; ++t) {
            s8v vb0 = *(const s8v*)&Vt[cur][t * 16 + r][g * 8];
            s8v vb1 = *(const s8v*)&Vt[cur][t * 16 + r][32 + g * 8];
            o[t] = mfma16(pa0, vb0, o[t]);
            o[t] = mfma16(pa1, vb1, o[t]);
        }
        __builtin_amdgcn_s_setprio(0);
        __syncthreads();          // single barrier: flips buffers
    }

    // epilogue: O * (1/l), l broadcast from row-lanes to output layout
    float rl = __builtin_amdgcn_rcpf(lrow);
    float rlq[4];
    #pragma unroll
    for (int q = 0; q < 4; ++q) rlq[q] = __shfl(rl, g * 4 + q, 64);
    #pragma unroll
    for (int t = 0; t < 4; ++t)
        #pragma unroll
        for (int q = 0; q < 4; ++q)
            O[(size_t)(qb + wid * 16 + g * 4 + q) * 2048 + h * 64 + t * 16 + r] =
                f2bf_bits(o[t][q] * rlq[q]);
}

extern "C" void kernel_launch(void* const* d_in, const int* in_sizes, int n_in,
                              void* d_out, int out_size, void* d_ws, size_t ws_size,
                              hipStream_t stream)
{
    const float* x  = (const float*)d_in[0];
    const float* fc = (const float*)d_in[1];
    const float* fs = (const float*)d_in[2];
    // d_in[3] = mask (unused; causal applied analytically)
    const float* wq = (const float*)d_in[4];
    const float* wk = (const float*)d_in[5];
    const float* wv = (const float*)d_in[6];
    const float* wo = (const float*)d_in[7];
    float* out = (float*)d_out;

    char* ws = (char*)d_ws;
    short* xb    = (short*)(ws);                         //  8 MB: 2048x2048 (reused as gemm1 P3)
    short* wqkvT = (short*)(ws + 8  * 1024 * 1024);      // 12 MB: 3072x2048
    short* woT   = (short*)(ws + 20 * 1024 * 1024);      //  8 MB: 2048x2048
    short* qkv   = (short*)(ws + 28 * 1024 * 1024);      // 12 MB: 2048x3072 (reused as gemm1 P2)
    short* vT    = (short*)(ws + 40 * 1024 * 1024);      //  2 MB: 512x2048
    short* attnO = (short*)(ws + 42 * 1024 * 1024);      //  8 MB: 2048x2048
    short* P0    = (short*)(ws + 50 * 1024 * 1024);      // 13 MB partial
    short* P1    = (short*)(ws + 63 * 1024 * 1024);      // 13 MB partial

    prep<<<14336, 256, 0, stream>>>(x, wq, wk, wv, wo, xb, wqkvT, woT);

    // QKV projection, split-K=2: 24x16 tiles x 2 = 768 blocks
    gemm_bt<2><<<768, 256, 0, stream>>>(xb, wqkvT, P0, P1, nullptr, nullptr, 3072, 2048, 24);
    ep1<<<3584, 256, 0, stream>>>(P0, P1, qkv, vT, fc, fs);

    flash_attn<<<dim3(32, 32), 256, 0, stream>>>(qkv, vT, attnO);

    // out projection, split-K=4: 16x16 tiles x 4 = 1024 blocks (P2 = qkv region, P3 = xb; both dead)
    gemm_bt<4><<<1024, 256, 0, stream>>>(attnO, woT, P0, P1, qkv, xb, 2048, 2048, 16);
    add_out4<<<2048, 256, 0, stream>>>(P0, P1, qkv, xb, out);
}